// Round 4
// baseline (1288.114 us; speedup 1.0000x reference)
//
#include <hip/hip_runtime.h>

#define WROW 52   // 13 time slices * 4 feats per node

typedef _Float16 half_t;
typedef _Float16 half8 __attribute__((ext_vector_type(8)));
typedef float f32x4 __attribute__((ext_vector_type(4)));

#define SC 0.0009765625f   // 2^-10, folded into an/bn at conv_proj store

// pack two f32 -> two f16 (RTZ) as a 32-bit word
__device__ __forceinline__ unsigned pkrtz(float a, float b) {
  auto v = __builtin_amdgcn_cvt_pkrtz(a, b);   // __fp16 x2
  return *(unsigned*)&v;
}

// ---------------- conv (2 layers) + edge-input projection -------------------
// LANES threads per node. cp: per-node scratch 160 floats:
//   [0..19] window (5 slices x 4), [32..127] h1 (3x32), [128..159] h2 (32)
// an/bn are stored PRE-SCALED by SC.
template<int LANES>
__device__ __forceinline__ void conv_proj(
    int lane, int gid, float* cp,
    const float* __restrict__ cw1, const float* __restrict__ cb1,
    const float* __restrict__ cw2, const float* __restrict__ cb2,
    const float* __restrict__ ew1,
    float* __restrict__ an, float* __restrict__ bn)
{
  #pragma unroll
  for (int o = 0; o < 96 / LANES; ++o) {
    int idx = lane + o * LANES;
    int tt = idx >> 5, f = idx & 31;
    float a = cb1[f];
    #pragma unroll
    for (int kt = 0; kt < 3; ++kt)
      #pragma unroll
      for (int d = 0; d < 4; ++d)
        a = fmaf(cp[(tt + kt) * 4 + d], cw1[(kt * 4 + d) * 32 + f], a);
    cp[32 + idx] = fmaxf(a, 0.f);
  }
  __syncthreads();
  #pragma unroll
  for (int o = 0; o < 32 / LANES; ++o) {
    int f = lane + o * LANES;
    float a = cb2[f];
    #pragma unroll
    for (int kt = 0; kt < 3; ++kt)
      for (int f1 = 0; f1 < 32; ++f1)
        a = fmaf(cp[32 + kt * 32 + f1], cw2[(kt * 32 + f1) * 32 + f], a);
    cp[128 + f] = fmaxf(a, 0.f);
  }
  __syncthreads();
  #pragma unroll
  for (int o = 0; o < 128 / LANES; ++o) {
    int j = lane + o * LANES;
    float a = 0.f, bb = 0.f;
    for (int f = 0; f < 32; ++f) {
      float h = cp[128 + f];
      a  = fmaf(h, ew1[f * 128 + j], a);
      bb = fmaf(h, ew1[(32 + f) * 128 + j], bb);
    }
    an[gid * 128 + j] = a * SC;
    bn[gid * 128 + j] = bb * SC;
  }
}

// ---------------- k_init: transpose + step-0 conv/proj ---------------------
__global__ __launch_bounds__(256) void k_init(
    const float* __restrict__ ts,
    const float* __restrict__ cw1, const float* __restrict__ cb1,
    const float* __restrict__ cw2, const float* __restrict__ cb2,
    const float* __restrict__ ew1,
    float* __restrict__ win, float* __restrict__ an, float* __restrict__ bn)
{
  __shared__ float cp[16 * 160];
  int blk = blockIdx.x;
  int b = blk >> 2, n0 = (blk & 3) << 4;
  int tid = threadIdx.x;
  int ln = tid >> 4, lane = tid & 15;
  int n = n0 + ln;
  int gid = b * 64 + n;
  float* mycp = cp + ln * 160;
  for (int idx = lane; idx < 20; idx += 16) {
    int tt = idx >> 2, d = idx & 3;
    float v = ts[((b * 5 + tt) * 64 + n) * 4 + d];
    mycp[idx] = v;
    win[gid * WROW + idx] = v;
  }
  __syncthreads();
  conv_proj<16>(lane, gid, mycp, cw1, cb1, cw2, cb2, ew1, an, bn);
}

// ---------------- k_bsplit: ew2 -> fp16 hi/lo in MFMA-fragment layout ------
__global__ __launch_bounds__(256) void k_bsplit(
    const float* __restrict__ ew2, half_t* __restrict__ Bh, half_t* __restrict__ Bl)
{
  int g = blockIdx.x * 256 + threadIdx.x;   // 0..16383 : k*128+col
  int k = g >> 7, col = g & 127;
  float x = ew2[g];
  _Float16 hi = (_Float16)x;
  float lo = x - (float)hi;
  int c = col >> 4, kb = k >> 5, kk = k & 31;
  int lane = ((kk >> 3) << 4) | (col & 15);
  int j = kk & 7;
  int idx = ((c * 4 + kb) * 64 + lane) * 8 + j;
  Bh[idx] = hi;
  Bl[idx] = (_Float16)lo;
}

// ---------------- k_edge_mfma: per (b,t) 64x128 @ 128x128 via f16-split ----
// C = 1024 * (Ah@Bh + Ah@Bl + Al@Bh), A = relu(anS + btS)  (already *2^-10)
__global__ __launch_bounds__(256) void k_edge_mfma(
    const float* __restrict__ an, const float* __restrict__ bn,
    const float* __restrict__ eb1, const float* __restrict__ eb2,
    const half_t* __restrict__ Bh, const half_t* __restrict__ Bl,
    float* __restrict__ nm)
{
  __shared__ __align__(16) half_t sAh[8192];   // 16 KB, fragment-permuted
  __shared__ __align__(16) half_t sAl[8192];   // 16 KB
  __shared__ float s_bt[128], s_eb2[128];
  __shared__ float s_part[2][128];
  int blk = blockIdx.x;
  int b = blk >> 6, t = blk & 63;
  int tid = threadIdx.x;
  if (tid < 128) {
    s_bt[tid]  = bn[(b * 64 + t) * 128 + tid] + eb1[tid] * SC;
    s_eb2[tid] = eb2[tid];
  }
  __syncthreads();

  // split phase, WRITE-LINEAR: unit u writes halves [u*8 .. u*8+7] (byte u*16)
  // u = ((sgrp*4 + kb)*64 + lane), content row s = sgrp*16+(lane&15),
  // cols kb8*8 with kb8 = kb*4 + (lane>>4)  == MFMA A-fragment layout.
  #pragma unroll
  for (int it = 0; it < 4; ++it) {
    int u = tid + it * 256;
    int s   = ((u >> 8) << 4) | (u & 15);
    int kb8 = ((u >> 4) & 12) | ((u >> 4) & 3);   // (kb<<2)|kbl
    const float* ap = an + (((b << 6) + s) << 7) + (kb8 << 3);
    float4 x0 = *(const float4*)ap;
    float4 x1 = *(const float4*)(ap + 4);
    float4 b0 = *(const float4*)(s_bt + (kb8 << 3));
    float4 b1 = *(const float4*)(s_bt + (kb8 << 3) + 4);
    float xs[8] = {x0.x, x0.y, x0.z, x0.w, x1.x, x1.y, x1.z, x1.w};
    float bs[8] = {b0.x, b0.y, b0.z, b0.w, b1.x, b1.y, b1.z, b1.w};
    float h32[8], l32[8];
    #pragma unroll
    for (int i = 0; i < 8; ++i) {
      float x = fmaxf(xs[i] + bs[i], 0.f);
      float h = __uint_as_float(__float_as_uint(x) & 0xffffe000u);  // exact f16-RTZ hi
      h32[i] = h;
      l32[i] = x - h;
    }
    unsigned hw[4], lw[4];
    #pragma unroll
    for (int p = 0; p < 4; ++p) {
      hw[p] = pkrtz(h32[2*p], h32[2*p+1]);
      lw[p] = pkrtz(l32[2*p], l32[2*p+1]);
    }
    *(uint4*)(sAh + u * 8) = make_uint4(hw[0], hw[1], hw[2], hw[3]);
    *(uint4*)(sAl + u * 8) = make_uint4(lw[0], lw[1], lw[2], lw[3]);
  }
  __syncthreads();

  // MFMA phase: wave w -> rows (w>>1)*32..+31, cols (w&1)*64..+63
  int w = tid >> 6, lane = tid & 63;
  int wr = w >> 1, wc = w & 1;
  f32x4 acc[2][4];
  #pragma unroll
  for (int rr = 0; rr < 2; ++rr)
    #pragma unroll
    for (int cc = 0; cc < 4; ++cc)
      acc[rr][cc] = (f32x4){0.f, 0.f, 0.f, 0.f};

  #pragma unroll
  for (int kb = 0; kb < 4; ++kb) {
    half8 ah[2], al[2];
    #pragma unroll
    for (int rr = 0; rr < 2; ++rr) {
      int r = wr * 2 + rr;
      ah[rr] = *(half8*)(sAh + ((r * 4 + kb) * 64 + lane) * 8);
      al[rr] = *(half8*)(sAl + ((r * 4 + kb) * 64 + lane) * 8);
    }
    #pragma unroll
    for (int cc = 0; cc < 4; ++cc) {
      int c = wc * 4 + cc;
      half8 bh = *(const half8*)(Bh + ((c * 4 + kb) * 64 + lane) * 8);
      half8 bl = *(const half8*)(Bl + ((c * 4 + kb) * 64 + lane) * 8);
      #pragma unroll
      for (int rr = 0; rr < 2; ++rr) {
        acc[rr][cc] = __builtin_amdgcn_mfma_f32_16x16x32_f16(ah[rr], bh, acc[rr][cc], 0, 0, 0);
        acc[rr][cc] = __builtin_amdgcn_mfma_f32_16x16x32_f16(ah[rr], bl, acc[rr][cc], 0, 0, 0);
        acc[rr][cc] = __builtin_amdgcn_mfma_f32_16x16x32_f16(al[rr], bh, acc[rr][cc], 0, 0, 0);
      }
    }
  }

  // epilogue: bias + relu per (s,col), mask s==t, sum rows
  float csum[4] = {0.f, 0.f, 0.f, 0.f};
  int colbase = lane & 15;
  int rowoff  = (lane >> 4) * 4;
  #pragma unroll
  for (int cc = 0; cc < 4; ++cc) {
    int col = (wc * 4 + cc) * 16 + colbase;
    float bias = s_eb2[col];
    #pragma unroll
    for (int rr = 0; rr < 2; ++rr) {
      int sbase = (wr * 2 + rr) * 16 + rowoff;
      #pragma unroll
      for (int q = 0; q < 4; ++q) {
        int s = sbase + q;
        float y = acc[rr][cc][q] * 1024.f + bias;
        if (s != t) csum[cc] += fmaxf(y, 0.f);
      }
    }
  }
  #pragma unroll
  for (int cc = 0; cc < 4; ++cc) {
    csum[cc] += __shfl_xor(csum[cc], 16, 64);
    csum[cc] += __shfl_xor(csum[cc], 32, 64);
  }
  if (lane < 16) {
    #pragma unroll
    for (int cc = 0; cc < 4; ++cc)
      s_part[wr][(wc * 4 + cc) * 16 + lane] = csum[cc];
  }
  __syncthreads();
  if (tid < 128)
    nm[(b * 64 + t) * 128 + tid] = s_part[0][tid] + s_part[1][tid];
}

// ---------------- dense layer helper: Y = relu(X @ W + b), 8 rows ----------
// thread = (half 0..1) x (j 0..127); half covers rows half*4..half*4+3
__device__ __forceinline__ void layer8(const float (*Xs)[132], float (*Ys)[132],
                                       const float* __restrict__ W,
                                       const float* __restrict__ bias, int tid)
{
  int j = tid & 127, nh = tid >> 7;
  float acc[4] = {0.f, 0.f, 0.f, 0.f};
  for (int i0 = 0; i0 < 128; i0 += 4) {
    float4 xv0 = *(const float4*)&Xs[(nh << 2) + 0][i0];
    float4 xv1 = *(const float4*)&Xs[(nh << 2) + 1][i0];
    float4 xv2 = *(const float4*)&Xs[(nh << 2) + 2][i0];
    float4 xv3 = *(const float4*)&Xs[(nh << 2) + 3][i0];
    #pragma unroll
    for (int k = 0; k < 4; ++k) {
      float w = W[(i0 + k) * 128 + j];
      acc[0] = fmaf(((const float*)&xv0)[k], w, acc[0]);
      acc[1] = fmaf(((const float*)&xv1)[k], w, acc[1]);
      acc[2] = fmaf(((const float*)&xv2)[k], w, acc[2]);
      acc[3] = fmaf(((const float*)&xv3)[k], w, acc[3]);
    }
  }
  float bj = bias[j];
  #pragma unroll
  for (int q = 0; q < 4; ++q) Ys[(nh << 2) + q][j] = fmaxf(acc[q] + bj, 0.f);
}

// ---------------- k_nd: node MLP + decoder + write nxt + next conv/proj ----
// 8 nodes per block, 1024 blocks
__global__ __launch_bounds__(256) void k_nd(
    int step,
    const float* __restrict__ nm,
    const float* __restrict__ nw1, const float* __restrict__ nb1,
    const float* __restrict__ nw2, const float* __restrict__ nb2,
    const float* __restrict__ dw1, const float* __restrict__ db1,
    const float* __restrict__ dw2, const float* __restrict__ db2,
    const float* __restrict__ ow,  const float* __restrict__ ob,
    const float* __restrict__ cw1, const float* __restrict__ cb1,
    const float* __restrict__ cw2, const float* __restrict__ cb2,
    const float* __restrict__ ew1,
    float* __restrict__ win, float* __restrict__ an, float* __restrict__ bn,
    float* __restrict__ out)
{
  __shared__ __align__(16) float X[8][132];
  __shared__ __align__(16) float Y[8][132];
  __shared__ float P[8][4];
  __shared__ float cp[8 * 160];
  int blk = blockIdx.x;
  int b = blk >> 3, n0 = (blk & 7) << 3;
  int tid = threadIdx.x;

  for (int idx = tid; idx < 1024; idx += 256) {
    int ln = idx >> 7, j = idx & 127;
    X[ln][j] = nm[((b * 64 + n0 + ln) * 128) + j];
  }
  if (tid < 32) {
    int ln = tid >> 2, d = tid & 3;
    P[ln][d] = win[(b * 64 + n0 + ln) * WROW + (step + 4) * 4 + d];
  }
  __syncthreads();
  layer8(X, Y, nw1, nb1, tid);   // node mlp 1
  __syncthreads();
  layer8(Y, X, nw2, nb2, tid);   // node mlp 2 -> node_msg in X
  __syncthreads();
  // dec1: Y = relu([P, X] @ dw1 + db1)
  {
    int j = tid & 127, nh = tid >> 7;
    float acc[4];
    #pragma unroll
    for (int q = 0; q < 4; ++q) {
      acc[q] = 0.f;
      #pragma unroll
      for (int d = 0; d < 4; ++d)
        acc[q] = fmaf(P[(nh << 2) + q][d], dw1[d * 128 + j], acc[q]);
    }
    const float* W = dw1 + 4 * 128;
    for (int i0 = 0; i0 < 128; i0 += 4) {
      float4 xv0 = *(const float4*)&X[(nh << 2) + 0][i0];
      float4 xv1 = *(const float4*)&X[(nh << 2) + 1][i0];
      float4 xv2 = *(const float4*)&X[(nh << 2) + 2][i0];
      float4 xv3 = *(const float4*)&X[(nh << 2) + 3][i0];
      #pragma unroll
      for (int k = 0; k < 4; ++k) {
        float w = W[(i0 + k) * 128 + j];
        acc[0] = fmaf(((const float*)&xv0)[k], w, acc[0]);
        acc[1] = fmaf(((const float*)&xv1)[k], w, acc[1]);
        acc[2] = fmaf(((const float*)&xv2)[k], w, acc[2]);
        acc[3] = fmaf(((const float*)&xv3)[k], w, acc[3]);
      }
    }
    float bj = db1[j];
    #pragma unroll
    for (int q = 0; q < 4; ++q) Y[(nh << 2) + q][j] = fmaxf(acc[q] + bj, 0.f);
  }
  __syncthreads();
  layer8(Y, X, dw2, db2, tid);   // dec2 -> X
  __syncthreads();
  // output head: nxt = X @ ow + ob + prev
  if (tid < 32) {
    int ln = tid >> 2, d = tid & 3;
    float a = ob[d] + P[ln][d];
    for (int i = 0; i < 128; ++i) a = fmaf(X[ln][i], ow[i * 4 + d], a);
    int n = n0 + ln, gid = b * 64 + n;
    win[gid * WROW + (step + 5) * 4 + d] = a;
    out[((b * 8 + step) * 64 + n) * 4 + d] = a;
    Y[ln][d] = a;                 // keep nxt in LDS for conv phase
  }
  __syncthreads();
  if (step < 7) {
    int ln = tid >> 5, lane = tid & 31;
    int gid = b * 64 + n0 + ln;
    float* mycp = cp + ln * 160;
    if (lane < 20) {
      float v = (lane < 16) ? win[gid * WROW + (step + 1) * 4 + lane]
                            : Y[ln][lane - 16];
      mycp[lane] = v;
    }
    __syncthreads();
    conv_proj<32>(lane, gid, mycp, cw1, cb1, cw2, cb2, ew1, an, bn);
  }
}

extern "C" void kernel_launch(void* const* d_in, const int* in_sizes, int n_in,
                              void* d_out, int out_size, void* d_ws, size_t ws_size,
                              hipStream_t stream) {
  (void)in_sizes; (void)n_in; (void)out_size; (void)ws_size;
  const float* ts  = (const float*)d_in[0];
  const float* cw1 = (const float*)d_in[1];
  const float* cb1 = (const float*)d_in[2];
  const float* cw2 = (const float*)d_in[3];
  const float* cb2 = (const float*)d_in[4];
  const float* ew1 = (const float*)d_in[5];
  const float* eb1 = (const float*)d_in[6];
  const float* ew2 = (const float*)d_in[7];
  const float* eb2 = (const float*)d_in[8];
  const float* nw1 = (const float*)d_in[9];
  const float* nb1 = (const float*)d_in[10];
  const float* nw2 = (const float*)d_in[11];
  const float* nb2 = (const float*)d_in[12];
  const float* dw1 = (const float*)d_in[13];
  const float* db1 = (const float*)d_in[14];
  const float* dw2 = (const float*)d_in[15];
  const float* db2 = (const float*)d_in[16];
  const float* ow  = (const float*)d_in[17];
  const float* ob  = (const float*)d_in[18];
  float* out = (float*)d_out;
  float* ws  = (float*)d_ws;
  float* win = ws;                       // 425984 floats
  float* an  = win + 425984;             // 1048576
  float* bn  = an + 1048576;             // 1048576
  float* nmb = bn + 1048576;             // 1048576
  half_t* Bh = (half_t*)(nmb + 1048576); // 16384 halves
  half_t* Bl = Bh + 16384;               // 16384 halves

  hipLaunchKernelGGL(k_bsplit, dim3(64), dim3(256), 0, stream, ew2, Bh, Bl);
  hipLaunchKernelGGL(k_init, dim3(512), dim3(256), 0, stream,
                     ts, cw1, cb1, cw2, cb2, ew1, win, an, bn);
  for (int k = 0; k < 8; ++k) {
    hipLaunchKernelGGL(k_edge_mfma, dim3(8192), dim3(256), 0, stream,
                       an, bn, eb1, eb2, Bh, Bl, nmb);
    hipLaunchKernelGGL(k_nd, dim3(1024), dim3(256), 0, stream,
                       k, nmb, nw1, nb1, nw2, nb2, dw1, db1, dw2, db2,
                       ow, ob, cw1, cb1, cw2, cb2, ew1, win, an, bn, out);
  }
}

// Round 5
// 780.997 us; speedup vs baseline: 1.6493x; 1.6493x over previous
//
#include <hip/hip_runtime.h>

#define WROW 52   // 13 time slices * 4 feats per node
#define TG 16     // targets per k_edge block

typedef _Float16 half_t;
typedef _Float16 half8 __attribute__((ext_vector_type(8)));
typedef float f32x4 __attribute__((ext_vector_type(4)));

#define SC 0.0009765625f   // 2^-10, folded into an/bn at conv_proj store

// pack two f32 -> two f16 (RTZ) as a 32-bit word
__device__ __forceinline__ unsigned pkrtz(float a, float b) {
  auto v = __builtin_amdgcn_cvt_pkrtz(a, b);   // __fp16 x2
  return *(unsigned*)&v;
}

// ---------------- conv (2 layers) + edge-input projection -------------------
// LANES threads per node. cp: per-node scratch 160 floats.
// an/bn are stored PRE-SCALED by SC.
template<int LANES>
__device__ __forceinline__ void conv_proj(
    int lane, int gid, float* cp,
    const float* __restrict__ cw1, const float* __restrict__ cb1,
    const float* __restrict__ cw2, const float* __restrict__ cb2,
    const float* __restrict__ ew1,
    float* __restrict__ an, float* __restrict__ bn)
{
  #pragma unroll
  for (int o = 0; o < 96 / LANES; ++o) {
    int idx = lane + o * LANES;
    int tt = idx >> 5, f = idx & 31;
    float a = cb1[f];
    #pragma unroll
    for (int kt = 0; kt < 3; ++kt)
      #pragma unroll
      for (int d = 0; d < 4; ++d)
        a = fmaf(cp[(tt + kt) * 4 + d], cw1[(kt * 4 + d) * 32 + f], a);
    cp[32 + idx] = fmaxf(a, 0.f);
  }
  __syncthreads();
  #pragma unroll
  for (int o = 0; o < 32 / LANES; ++o) {
    int f = lane + o * LANES;
    float a = cb2[f];
    #pragma unroll
    for (int kt = 0; kt < 3; ++kt)
      for (int f1 = 0; f1 < 32; ++f1)
        a = fmaf(cp[32 + kt * 32 + f1], cw2[(kt * 32 + f1) * 32 + f], a);
    cp[128 + f] = fmaxf(a, 0.f);
  }
  __syncthreads();
  #pragma unroll
  for (int o = 0; o < 128 / LANES; ++o) {
    int j = lane + o * LANES;
    float a = 0.f, bb = 0.f;
    for (int f = 0; f < 32; ++f) {
      float h = cp[128 + f];
      a  = fmaf(h, ew1[f * 128 + j], a);
      bb = fmaf(h, ew1[(32 + f) * 128 + j], bb);
    }
    an[gid * 128 + j] = a * SC;
    bn[gid * 128 + j] = bb * SC;
  }
}

// ---------------- k_init: transpose + step-0 conv/proj ---------------------
__global__ __launch_bounds__(256) void k_init(
    const float* __restrict__ ts,
    const float* __restrict__ cw1, const float* __restrict__ cb1,
    const float* __restrict__ cw2, const float* __restrict__ cb2,
    const float* __restrict__ ew1,
    float* __restrict__ win, float* __restrict__ an, float* __restrict__ bn)
{
  __shared__ float cp[16 * 160];
  int blk = blockIdx.x;
  int b = blk >> 2, n0 = (blk & 3) << 4;
  int tid = threadIdx.x;
  int ln = tid >> 4, lane = tid & 15;
  int n = n0 + ln;
  int gid = b * 64 + n;
  float* mycp = cp + ln * 160;
  for (int idx = lane; idx < 20; idx += 16) {
    int tt = idx >> 2, d = idx & 3;
    float v = ts[((b * 5 + tt) * 64 + n) * 4 + d];
    mycp[idx] = v;
    win[gid * WROW + idx] = v;
  }
  __syncthreads();
  conv_proj<16>(lane, gid, mycp, cw1, cb1, cw2, cb2, ew1, an, bn);
}

// ---------------- k_bsplit: ew2 -> fp16 hi/lo in MFMA-fragment layout ------
__global__ __launch_bounds__(256) void k_bsplit(
    const float* __restrict__ ew2, half_t* __restrict__ Bh, half_t* __restrict__ Bl)
{
  int g = blockIdx.x * 256 + threadIdx.x;   // 0..16383 : k*128+col
  int k = g >> 7, col = g & 127;
  float x = ew2[g];
  _Float16 hi = (_Float16)x;
  float lo = x - (float)hi;
  int c = col >> 4, kb = k >> 5, kk = k & 31;
  int lane = ((kk >> 3) << 4) | (col & 15);
  int j = kk & 7;
  int idx = ((c * 4 + kb) * 64 + lane) * 8 + j;
  Bh[idx] = hi;
  Bl[idx] = (_Float16)lo;
}

// ---------------- k_edge_v3: per (b, 16-target group) ----------------------
// Stage an[b] (64x128) in LDS once; loop 16 targets: split -> MFMA -> reduce.
// C = 1024 * (Ah@Bh + Ah@Bl + Al@Bh), A = relu(anS + btS)  (pre-scaled 2^-10)
__global__ __launch_bounds__(256, 2) void k_edge_v3(
    const float* __restrict__ an, const float* __restrict__ bn,
    const float* __restrict__ eb1, const float* __restrict__ eb2,
    const half_t* __restrict__ Bh, const half_t* __restrict__ Bl,
    float* __restrict__ nm)
{
  __shared__ __align__(16) float  s_an[8192];   // 32 KB raw [s][k]
  __shared__ __align__(16) half_t sAh[8192];    // 16 KB fragment-ordered
  __shared__ __align__(16) half_t sAl[8192];    // 16 KB
  __shared__ float s_bt[TG * 128];              // 8 KB
  __shared__ float s_eb2[128];
  __shared__ float s_part[2][128];
  int blk = blockIdx.x;
  int b = blk & 127, t0 = (blk >> 7) * TG;  // same-b groups share an XCD (%8)
  int tid = threadIdx.x;

  // stage an slice (coalesced float4), bt rows (+eb1*SC), eb2
  {
    const float4* src = (const float4*)(an + (b << 13));
    float4* dst = (float4*)s_an;
    #pragma unroll
    for (int i = 0; i < 8; ++i) dst[tid + (i << 8)] = src[tid + (i << 8)];
  }
  #pragma unroll
  for (int i = 0; i < TG * 128 / 256; ++i) {
    int idx = tid + (i << 8);
    int tt = idx >> 7, j = idx & 127;
    s_bt[idx] = bn[((b << 6) + t0 + tt) * 128 + j] + eb1[j] * SC;
  }
  if (tid < 128) s_eb2[tid] = eb2[tid];
  __syncthreads();

  int w = tid >> 6, lane = tid & 63;
  int wr = w >> 1, wc = w & 1;
  int colbase = lane & 15;
  int rowoff  = (lane >> 4) * 4;

  for (int tt = 0; tt < TG; ++tt) {
    int t = t0 + tt;
    // ---- split: relu(an+bt) -> f16 hi/lo, write-linear fragment layout ----
    #pragma unroll
    for (int it = 0; it < 4; ++it) {
      int u = tid + (it << 8);
      int s   = ((u >> 8) << 4) | (u & 15);
      int kb8 = (u >> 4) & 15;                 // kb*4 + kbl
      const float* ap = s_an + (s << 7) + (kb8 << 3);
      const float* bp = s_bt + (tt << 7) + (kb8 << 3);
      float4 x0 = *(const float4*)ap;
      float4 x1 = *(const float4*)(ap + 4);
      float4 b0 = *(const float4*)bp;
      float4 b1 = *(const float4*)(bp + 4);
      float xs[8] = {x0.x, x0.y, x0.z, x0.w, x1.x, x1.y, x1.z, x1.w};
      float bs[8] = {b0.x, b0.y, b0.z, b0.w, b1.x, b1.y, b1.z, b1.w};
      float h32[8], l32[8];
      #pragma unroll
      for (int i = 0; i < 8; ++i) {
        float x = fmaxf(xs[i] + bs[i], 0.f);
        float h = __uint_as_float(__float_as_uint(x) & 0xffffe000u);
        h32[i] = h;
        l32[i] = x - h;
      }
      unsigned hw[4], lw[4];
      #pragma unroll
      for (int p = 0; p < 4; ++p) {
        hw[p] = pkrtz(h32[2*p], h32[2*p+1]);
        lw[p] = pkrtz(l32[2*p], l32[2*p+1]);
      }
      *(uint4*)(sAh + u * 8) = make_uint4(hw[0], hw[1], hw[2], hw[3]);
      *(uint4*)(sAl + u * 8) = make_uint4(lw[0], lw[1], lw[2], lw[3]);
    }
    __syncthreads();

    // ---- MFMA: wave w -> rows wr*32..+31, cols wc*64..+63 ----
    f32x4 acc[2][4];
    #pragma unroll
    for (int rr = 0; rr < 2; ++rr)
      #pragma unroll
      for (int cc = 0; cc < 4; ++cc)
        acc[rr][cc] = (f32x4){0.f, 0.f, 0.f, 0.f};

    #pragma unroll
    for (int kb = 0; kb < 4; ++kb) {
      half8 ah[2], al[2];
      #pragma unroll
      for (int rr = 0; rr < 2; ++rr) {
        int r = wr * 2 + rr;
        ah[rr] = *(half8*)(sAh + ((r * 4 + kb) * 64 + lane) * 8);
        al[rr] = *(half8*)(sAl + ((r * 4 + kb) * 64 + lane) * 8);
      }
      #pragma unroll
      for (int cc = 0; cc < 4; ++cc) {
        int c = wc * 4 + cc;
        half8 bh = *(const half8*)(Bh + ((c * 4 + kb) * 64 + lane) * 8);
        half8 bl = *(const half8*)(Bl + ((c * 4 + kb) * 64 + lane) * 8);
        #pragma unroll
        for (int rr = 0; rr < 2; ++rr) {
          acc[rr][cc] = __builtin_amdgcn_mfma_f32_16x16x32_f16(ah[rr], bh, acc[rr][cc], 0, 0, 0);
          acc[rr][cc] = __builtin_amdgcn_mfma_f32_16x16x32_f16(ah[rr], bl, acc[rr][cc], 0, 0, 0);
          acc[rr][cc] = __builtin_amdgcn_mfma_f32_16x16x32_f16(al[rr], bh, acc[rr][cc], 0, 0, 0);
        }
      }
    }

    // ---- epilogue: bias+relu, mask s==t, reduce rows -> nm[b,t] ----
    float csum[4] = {0.f, 0.f, 0.f, 0.f};
    #pragma unroll
    for (int cc = 0; cc < 4; ++cc) {
      int col = (wc * 4 + cc) * 16 + colbase;
      float bias = s_eb2[col];
      #pragma unroll
      for (int rr = 0; rr < 2; ++rr) {
        int sbase = (wr * 2 + rr) * 16 + rowoff;
        #pragma unroll
        for (int q = 0; q < 4; ++q) {
          int s = sbase + q;
          float y = acc[rr][cc][q] * 1024.f + bias;
          if (s != t) csum[cc] += fmaxf(y, 0.f);
        }
      }
    }
    #pragma unroll
    for (int cc = 0; cc < 4; ++cc) {
      csum[cc] += __shfl_xor(csum[cc], 16, 64);
      csum[cc] += __shfl_xor(csum[cc], 32, 64);
    }
    if (lane < 16) {
      #pragma unroll
      for (int cc = 0; cc < 4; ++cc)
        s_part[wr][(wc * 4 + cc) * 16 + lane] = csum[cc];
    }
    __syncthreads();
    if (tid < 128)
      nm[((b << 6) + t) * 128 + tid] = s_part[0][tid] + s_part[1][tid];
    __syncthreads();   // protect s_part / sAh before next tt
  }
}

// ---------------- dense layer helper: Y = relu(X @ W + b), 16 rows ---------
__device__ __forceinline__ void layer16(const float (*Xs)[132], float (*Ys)[132],
                                        const float* __restrict__ W,
                                        const float* __restrict__ bias, int tid)
{
  int j = tid & 127, nh = tid >> 7;
  float acc[8] = {0.f,0.f,0.f,0.f,0.f,0.f,0.f,0.f};
  for (int i = 0; i < 128; ++i) {
    float w = W[i * 128 + j];
    #pragma unroll
    for (int q = 0; q < 8; ++q) acc[q] = fmaf(Xs[(nh << 3) + q][i], w, acc[q]);
  }
  float bj = bias[j];
  #pragma unroll
  for (int q = 0; q < 8; ++q) Ys[(nh << 3) + q][j] = fmaxf(acc[q] + bj, 0.f);
}

// ---------------- k_nd: node MLP + decoder + write nxt + next conv/proj ----
// (reverted to the proven R2 structure: 16 nodes/block, 512 blocks)
__global__ __launch_bounds__(256) void k_nd(
    int step,
    const float* __restrict__ nm,
    const float* __restrict__ nw1, const float* __restrict__ nb1,
    const float* __restrict__ nw2, const float* __restrict__ nb2,
    const float* __restrict__ dw1, const float* __restrict__ db1,
    const float* __restrict__ dw2, const float* __restrict__ db2,
    const float* __restrict__ ow,  const float* __restrict__ ob,
    const float* __restrict__ cw1, const float* __restrict__ cb1,
    const float* __restrict__ cw2, const float* __restrict__ cb2,
    const float* __restrict__ ew1,
    float* __restrict__ win, float* __restrict__ an, float* __restrict__ bn,
    float* __restrict__ out)
{
  __shared__ __align__(16) float X[16][132];
  __shared__ __align__(16) float Y[16][132];
  __shared__ float P[16][4];
  __shared__ float cp[16 * 160];
  int blk = blockIdx.x;
  int b = blk >> 2, n0 = (blk & 3) << 4;
  int tid = threadIdx.x;

  for (int idx = tid; idx < 2048; idx += 256) {
    int ln = idx >> 7, j = idx & 127;
    X[ln][j] = nm[((b * 64 + n0 + ln) * 128) + j];
  }
  if (tid < 64) {
    int ln = tid >> 2, d = tid & 3;
    P[ln][d] = win[(b * 64 + n0 + ln) * WROW + (step + 4) * 4 + d];
  }
  __syncthreads();
  layer16(X, Y, nw1, nb1, tid);   // node mlp 1
  __syncthreads();
  layer16(Y, X, nw2, nb2, tid);   // node mlp 2 -> node_msg in X
  __syncthreads();
  // dec1: Y = relu([P, X] @ dw1 + db1)
  {
    int j = tid & 127, nh = tid >> 7;
    float acc[8];
    #pragma unroll
    for (int q = 0; q < 8; ++q) {
      acc[q] = 0.f;
      #pragma unroll
      for (int d = 0; d < 4; ++d)
        acc[q] = fmaf(P[(nh << 3) + q][d], dw1[d * 128 + j], acc[q]);
    }
    const float* W = dw1 + 4 * 128;
    for (int i = 0; i < 128; ++i) {
      float w = W[i * 128 + j];
      #pragma unroll
      for (int q = 0; q < 8; ++q) acc[q] = fmaf(X[(nh << 3) + q][i], w, acc[q]);
    }
    float bj = db1[j];
    #pragma unroll
    for (int q = 0; q < 8; ++q) Y[(nh << 3) + q][j] = fmaxf(acc[q] + bj, 0.f);
  }
  __syncthreads();
  layer16(Y, X, dw2, db2, tid);   // dec2 -> X
  __syncthreads();
  // output head: nxt = X @ ow + ob + prev
  if (tid < 64) {
    int ln = tid >> 2, d = tid & 3;
    float a = ob[d] + P[ln][d];
    for (int i = 0; i < 128; ++i) a = fmaf(X[ln][i], ow[i * 4 + d], a);
    int n = n0 + ln, gid = b * 64 + n;
    win[gid * WROW + (step + 5) * 4 + d] = a;
    out[((b * 8 + step) * 64 + n) * 4 + d] = a;
    Y[ln][d] = a;                 // keep nxt in LDS for conv phase
  }
  __syncthreads();
  if (step < 7) {
    int ln = tid >> 4, lane = tid & 15;
    int gid = b * 64 + n0 + ln;
    float* mycp = cp + ln * 160;
    mycp[lane] = win[gid * WROW + (step + 1) * 4 + lane];
    if (lane < 4) mycp[16 + lane] = Y[ln][lane];
    __syncthreads();
    conv_proj<16>(lane, gid, mycp, cw1, cb1, cw2, cb2, ew1, an, bn);
  }
}

extern "C" void kernel_launch(void* const* d_in, const int* in_sizes, int n_in,
                              void* d_out, int out_size, void* d_ws, size_t ws_size,
                              hipStream_t stream) {
  (void)in_sizes; (void)n_in; (void)out_size; (void)ws_size;
  const float* ts  = (const float*)d_in[0];
  const float* cw1 = (const float*)d_in[1];
  const float* cb1 = (const float*)d_in[2];
  const float* cw2 = (const float*)d_in[3];
  const float* cb2 = (const float*)d_in[4];
  const float* ew1 = (const float*)d_in[5];
  const float* eb1 = (const float*)d_in[6];
  const float* ew2 = (const float*)d_in[7];
  const float* eb2 = (const float*)d_in[8];
  const float* nw1 = (const float*)d_in[9];
  const float* nb1 = (const float*)d_in[10];
  const float* nw2 = (const float*)d_in[11];
  const float* nb2 = (const float*)d_in[12];
  const float* dw1 = (const float*)d_in[13];
  const float* db1 = (const float*)d_in[14];
  const float* dw2 = (const float*)d_in[15];
  const float* db2 = (const float*)d_in[16];
  const float* ow  = (const float*)d_in[17];
  const float* ob  = (const float*)d_in[18];
  float* out = (float*)d_out;
  float* ws  = (float*)d_ws;
  float* win = ws;                       // 425984 floats
  float* an  = win + 425984;             // 1048576
  float* bn  = an + 1048576;             // 1048576
  float* nmb = bn + 1048576;             // 1048576
  half_t* Bh = (half_t*)(nmb + 1048576); // 16384 halves
  half_t* Bl = Bh + 16384;               // 16384 halves

  hipLaunchKernelGGL(k_bsplit, dim3(64), dim3(256), 0, stream, ew2, Bh, Bl);
  hipLaunchKernelGGL(k_init, dim3(512), dim3(256), 0, stream,
                     ts, cw1, cb1, cw2, cb2, ew1, win, an, bn);
  for (int k = 0; k < 8; ++k) {
    hipLaunchKernelGGL(k_edge_v3, dim3(512), dim3(256), 0, stream,
                       an, bn, eb1, eb2, Bh, Bl, nmb);
    hipLaunchKernelGGL(k_nd, dim3(512), dim3(256), 0, stream,
                       k, nmb, nw1, nb1, nw2, nb2, dw1, db1, dw2, db2,
                       ow, ob, cw1, cb1, cw2, cb2, ew1, win, an, bn, out);
  }
}

// Round 6
// 721.771 us; speedup vs baseline: 1.7847x; 1.0821x over previous
//
#include <hip/hip_runtime.h>

#define WROW 52   // 13 time slices * 4 feats per node
#define TG 16     // targets per k_edge block

typedef _Float16 half_t;
typedef _Float16 half8 __attribute__((ext_vector_type(8)));
typedef float f32x4 __attribute__((ext_vector_type(4)));

#define SC 0.0009765625f   // 2^-10, folded into an/bn at conv_proj store

// pack two f32 -> two f16 (RTZ) as a 32-bit word
__device__ __forceinline__ unsigned pkrtz(float a, float b) {
  auto v = __builtin_amdgcn_cvt_pkrtz(a, b);   // __fp16 x2
  return *(unsigned*)&v;
}

// ---------------- conv (2 layers) + edge-input projection -------------------
// LANES threads per node. cp: per-node scratch 160 floats.
// an/bn are stored PRE-SCALED by SC.
template<int LANES>
__device__ __forceinline__ void conv_proj(
    int lane, int gid, float* cp,
    const float* __restrict__ cw1, const float* __restrict__ cb1,
    const float* __restrict__ cw2, const float* __restrict__ cb2,
    const float* __restrict__ ew1,
    float* __restrict__ an, float* __restrict__ bn)
{
  #pragma unroll
  for (int o = 0; o < 96 / LANES; ++o) {
    int idx = lane + o * LANES;
    int tt = idx >> 5, f = idx & 31;
    float a = cb1[f];
    #pragma unroll
    for (int kt = 0; kt < 3; ++kt)
      #pragma unroll
      for (int d = 0; d < 4; ++d)
        a = fmaf(cp[(tt + kt) * 4 + d], cw1[(kt * 4 + d) * 32 + f], a);
    cp[32 + idx] = fmaxf(a, 0.f);
  }
  __syncthreads();
  #pragma unroll
  for (int o = 0; o < 32 / LANES; ++o) {
    int f = lane + o * LANES;
    float a = cb2[f];
    #pragma unroll
    for (int kt = 0; kt < 3; ++kt)
      for (int f1 = 0; f1 < 32; ++f1)
        a = fmaf(cp[32 + kt * 32 + f1], cw2[(kt * 32 + f1) * 32 + f], a);
    cp[128 + f] = fmaxf(a, 0.f);
  }
  __syncthreads();
  #pragma unroll
  for (int o = 0; o < 128 / LANES; ++o) {
    int j = lane + o * LANES;
    float a = 0.f, bb = 0.f;
    for (int f = 0; f < 32; ++f) {
      float h = cp[128 + f];
      a  = fmaf(h, ew1[f * 128 + j], a);
      bb = fmaf(h, ew1[(32 + f) * 128 + j], bb);
    }
    an[gid * 128 + j] = a * SC;
    bn[gid * 128 + j] = bb * SC;
  }
}

// ---------------- k_init: transpose + step-0 conv/proj ---------------------
__global__ __launch_bounds__(256) void k_init(
    const float* __restrict__ ts,
    const float* __restrict__ cw1, const float* __restrict__ cb1,
    const float* __restrict__ cw2, const float* __restrict__ cb2,
    const float* __restrict__ ew1,
    float* __restrict__ win, float* __restrict__ an, float* __restrict__ bn)
{
  __shared__ float cp[16 * 160];
  int blk = blockIdx.x;
  int b = blk >> 2, n0 = (blk & 3) << 4;
  int tid = threadIdx.x;
  int ln = tid >> 4, lane = tid & 15;
  int n = n0 + ln;
  int gid = b * 64 + n;
  float* mycp = cp + ln * 160;
  for (int idx = lane; idx < 20; idx += 16) {
    int tt = idx >> 2, d = idx & 3;
    float v = ts[((b * 5 + tt) * 64 + n) * 4 + d];
    mycp[idx] = v;
    win[gid * WROW + idx] = v;
  }
  __syncthreads();
  conv_proj<16>(lane, gid, mycp, cw1, cb1, cw2, cb2, ew1, an, bn);
}

// ---------------- k_bsplit: ew2 -> fp16 hi/lo in MFMA-fragment layout ------
__global__ __launch_bounds__(256) void k_bsplit(
    const float* __restrict__ ew2, half_t* __restrict__ Bh, half_t* __restrict__ Bl)
{
  int g = blockIdx.x * 256 + threadIdx.x;   // 0..16383 : k*128+col
  int k = g >> 7, col = g & 127;
  float x = ew2[g];
  _Float16 hi = (_Float16)x;
  float lo = x - (float)hi;
  int c = col >> 4, kb = k >> 5, kk = k & 31;
  int lane = ((kk >> 3) << 4) | (col & 15);
  int j = kk & 7;
  int idx = ((c * 4 + kb) * 64 + lane) * 8 + j;
  Bh[idx] = hi;
  Bl[idx] = (_Float16)lo;
}

// ---------------- k_edge_v4: per (b, 16-target group) ----------------------
// an slice held in REGISTERS (au); B fragments held in REGISTERS (tt-invariant);
// double-buffered sAh/sAl so split(tt+1) co-issues with MFMA(tt); 1 barrier/tt.
// Wave w owns cols w*32..w*32+31 for ALL 64 rows -> in-wave row reduction.
// C = 1024 * (Ah@Bh + Ah@Bl + Al@Bh), A = relu(anS + btS)  (pre-scaled 2^-10)
__global__ __launch_bounds__(256, 2) void k_edge_v4(
    const float* __restrict__ an, const float* __restrict__ bn,
    const float* __restrict__ eb1, const float* __restrict__ eb2,
    const half_t* __restrict__ Bh, const half_t* __restrict__ Bl,
    float* __restrict__ nm)
{
  __shared__ __align__(16) half_t sAh[2][8192];   // 2 x 16 KB, fragment-ordered
  __shared__ __align__(16) half_t sAl[2][8192];   // 2 x 16 KB
  __shared__ float s_bt[TG * 128];                // 8 KB
  int blk = blockIdx.x;
  int b = blk & 127, t0 = (blk >> 7) * TG;  // same-b groups share an XCD (%8)
  int tid = threadIdx.x;
  int w = tid >> 6, lane = tid & 63;

  // ---- stage bt rows (+eb1*SC) into LDS (coalesced) ----
  #pragma unroll
  for (int i = 0; i < TG * 128 / 256; ++i) {
    int idx = tid + (i << 8);
    int tt = idx >> 7, j = idx & 127;
    s_bt[idx] = bn[((b << 6) + t0 + tt) * 128 + j] + eb1[j] * SC;
  }

  // ---- stage this thread's an slice into registers ----
  // thread owns kb8 = tid>>4 (fixed), s = 16*it + (tid&15)
  float au[4][8];
  {
    int kb8 = tid >> 4, sl = tid & 15;
    #pragma unroll
    for (int it = 0; it < 4; ++it) {
      const float* ap = an + (b << 13) + ((it * 16 + sl) << 7) + (kb8 << 3);
      float4 x0 = *(const float4*)ap;
      float4 x1 = *(const float4*)(ap + 4);
      au[it][0] = x0.x; au[it][1] = x0.y; au[it][2] = x0.z; au[it][3] = x0.w;
      au[it][4] = x1.x; au[it][5] = x1.y; au[it][6] = x1.z; au[it][7] = x1.w;
    }
  }

  // ---- B fragments into registers (tt-invariant): cols (w*2+cc)*16.. ----
  half8 rbh[2][4], rbl[2][4];
  #pragma unroll
  for (int cc = 0; cc < 2; ++cc)
    #pragma unroll
    for (int kb = 0; kb < 4; ++kb) {
      int c = w * 2 + cc;
      rbh[cc][kb] = *(const half8*)(Bh + ((c * 4 + kb) * 64 + lane) * 8);
      rbl[cc][kb] = *(const half8*)(Bl + ((c * 4 + kb) * 64 + lane) * 8);
    }

  // per-thread output-column biases
  float bias0 = eb2[(w * 2 + 0) * 16 + (lane & 15)];
  float bias1 = eb2[(w * 2 + 1) * 16 + (lane & 15)];

  // split: relu(au + bt[tt]) -> f16 hi/lo into dst (write-linear, conflict-free)
  auto do_split = [&](int tt, half_t* dh, half_t* dl) {
    const float* bp = s_bt + (tt << 7) + ((tid >> 4) << 3);
    float4 b0 = *(const float4*)bp;
    float4 b1 = *(const float4*)(bp + 4);
    float bs[8] = {b0.x, b0.y, b0.z, b0.w, b1.x, b1.y, b1.z, b1.w};
    #pragma unroll
    for (int it = 0; it < 4; ++it) {
      int u = tid + (it << 8);
      float h32[8], l32[8];
      #pragma unroll
      for (int i = 0; i < 8; ++i) {
        float x = fmaxf(au[it][i] + bs[i], 0.f);
        float h = __uint_as_float(__float_as_uint(x) & 0xffffe000u);
        h32[i] = h;
        l32[i] = x - h;
      }
      unsigned hw[4], lw[4];
      #pragma unroll
      for (int p = 0; p < 4; ++p) {
        hw[p] = pkrtz(h32[2 * p], h32[2 * p + 1]);
        lw[p] = pkrtz(l32[2 * p], l32[2 * p + 1]);
      }
      *(uint4*)(dh + u * 8) = make_uint4(hw[0], hw[1], hw[2], hw[3]);
      *(uint4*)(dl + u * 8) = make_uint4(lw[0], lw[1], lw[2], lw[3]);
    }
  };

  __syncthreads();                 // s_bt ready
  do_split(0, sAh[0], sAl[0]);
  __syncthreads();                 // buf0 ready

  for (int tt = 0; tt < TG; ++tt) {
    int p = tt & 1;
    // issue next split (buf p^1) -- co-schedules with MFMA on buf p
    if (tt + 1 < TG) do_split(tt + 1, sAh[p ^ 1], sAl[p ^ 1]);

    const half_t* ph = sAh[p];
    const half_t* pl = sAl[p];
    f32x4 acc[4][2];
    #pragma unroll
    for (int rr = 0; rr < 4; ++rr)
      #pragma unroll
      for (int cc = 0; cc < 2; ++cc)
        acc[rr][cc] = (f32x4){0.f, 0.f, 0.f, 0.f};

    #pragma unroll
    for (int kb = 0; kb < 4; ++kb) {
      half8 ah[4], al[4];
      #pragma unroll
      for (int rr = 0; rr < 4; ++rr) {
        ah[rr] = *(const half8*)(ph + ((rr * 4 + kb) * 64 + lane) * 8);
        al[rr] = *(const half8*)(pl + ((rr * 4 + kb) * 64 + lane) * 8);
      }
      #pragma unroll
      for (int cc = 0; cc < 2; ++cc)
        #pragma unroll
        for (int rr = 0; rr < 4; ++rr) {
          acc[rr][cc] = __builtin_amdgcn_mfma_f32_16x16x32_f16(ah[rr], rbh[cc][kb], acc[rr][cc], 0, 0, 0);
          acc[rr][cc] = __builtin_amdgcn_mfma_f32_16x16x32_f16(ah[rr], rbl[cc][kb], acc[rr][cc], 0, 0, 0);
          acc[rr][cc] = __builtin_amdgcn_mfma_f32_16x16x32_f16(al[rr], rbh[cc][kb], acc[rr][cc], 0, 0, 0);
        }
    }

    // epilogue: bias+relu, mask s==t, in-wave row reduction, coalesced store
    int t = t0 + tt;
    float csum0 = 0.f, csum1 = 0.f;
    int rowoff = (lane >> 4) * 4;
    #pragma unroll
    for (int rr = 0; rr < 4; ++rr) {
      int sbase = rr * 16 + rowoff;
      #pragma unroll
      for (int q = 0; q < 4; ++q) {
        int s = sbase + q;
        float y0 = acc[rr][0][q] * 1024.f + bias0;
        float y1 = acc[rr][1][q] * 1024.f + bias1;
        if (s != t) {
          csum0 += fmaxf(y0, 0.f);
          csum1 += fmaxf(y1, 0.f);
        }
      }
    }
    csum0 += __shfl_xor(csum0, 16, 64);
    csum0 += __shfl_xor(csum0, 32, 64);
    csum1 += __shfl_xor(csum1, 16, 64);
    csum1 += __shfl_xor(csum1, 32, 64);
    if (lane < 32)
      nm[((b << 6) + t) * 128 + w * 32 + lane] = (lane < 16) ? csum0 : csum1;
    __syncthreads();   // buf p^1 complete; all reads of buf p done
  }
}

// ---------------- dense layer helper: Y = relu(X @ W + b), 16 rows ---------
__device__ __forceinline__ void layer16(const float (*Xs)[132], float (*Ys)[132],
                                        const float* __restrict__ W,
                                        const float* __restrict__ bias, int tid)
{
  int j = tid & 127, nh = tid >> 7;
  float acc[8] = {0.f,0.f,0.f,0.f,0.f,0.f,0.f,0.f};
  for (int i = 0; i < 128; ++i) {
    float w = W[i * 128 + j];
    #pragma unroll
    for (int q = 0; q < 8; ++q) acc[q] = fmaf(Xs[(nh << 3) + q][i], w, acc[q]);
  }
  float bj = bias[j];
  #pragma unroll
  for (int q = 0; q < 8; ++q) Ys[(nh << 3) + q][j] = fmaxf(acc[q] + bj, 0.f);
}

// ---------------- k_nd: node MLP + decoder + write nxt + next conv/proj ----
__global__ __launch_bounds__(256) void k_nd(
    int step,
    const float* __restrict__ nm,
    const float* __restrict__ nw1, const float* __restrict__ nb1,
    const float* __restrict__ nw2, const float* __restrict__ nb2,
    const float* __restrict__ dw1, const float* __restrict__ db1,
    const float* __restrict__ dw2, const float* __restrict__ db2,
    const float* __restrict__ ow,  const float* __restrict__ ob,
    const float* __restrict__ cw1, const float* __restrict__ cb1,
    const float* __restrict__ cw2, const float* __restrict__ cb2,
    const float* __restrict__ ew1,
    float* __restrict__ win, float* __restrict__ an, float* __restrict__ bn,
    float* __restrict__ out)
{
  __shared__ __align__(16) float X[16][132];
  __shared__ __align__(16) float Y[16][132];
  __shared__ float P[16][4];
  __shared__ float cp[16 * 160];
  int blk = blockIdx.x;
  int b = blk >> 2, n0 = (blk & 3) << 4;
  int tid = threadIdx.x;

  for (int idx = tid; idx < 2048; idx += 256) {
    int ln = idx >> 7, j = idx & 127;
    X[ln][j] = nm[((b * 64 + n0 + ln) * 128) + j];
  }
  if (tid < 64) {
    int ln = tid >> 2, d = tid & 3;
    P[ln][d] = win[(b * 64 + n0 + ln) * WROW + (step + 4) * 4 + d];
  }
  __syncthreads();
  layer16(X, Y, nw1, nb1, tid);   // node mlp 1
  __syncthreads();
  layer16(Y, X, nw2, nb2, tid);   // node mlp 2 -> node_msg in X
  __syncthreads();
  // dec1: Y = relu([P, X] @ dw1 + db1)
  {
    int j = tid & 127, nh = tid >> 7;
    float acc[8];
    #pragma unroll
    for (int q = 0; q < 8; ++q) {
      acc[q] = 0.f;
      #pragma unroll
      for (int d = 0; d < 4; ++d)
        acc[q] = fmaf(P[(nh << 3) + q][d], dw1[d * 128 + j], acc[q]);
    }
    const float* W = dw1 + 4 * 128;
    for (int i = 0; i < 128; ++i) {
      float w = W[i * 128 + j];
      #pragma unroll
      for (int q = 0; q < 8; ++q) acc[q] = fmaf(X[(nh << 3) + q][i], w, acc[q]);
    }
    float bj = db1[j];
    #pragma unroll
    for (int q = 0; q < 8; ++q) Y[(nh << 3) + q][j] = fmaxf(acc[q] + bj, 0.f);
  }
  __syncthreads();
  layer16(Y, X, dw2, db2, tid);   // dec2 -> X
  __syncthreads();
  // output head: nxt = X @ ow + ob + prev
  if (tid < 64) {
    int ln = tid >> 2, d = tid & 3;
    float a = ob[d] + P[ln][d];
    for (int i = 0; i < 128; ++i) a = fmaf(X[ln][i], ow[i * 4 + d], a);
    int n = n0 + ln, gid = b * 64 + n;
    win[gid * WROW + (step + 5) * 4 + d] = a;
    out[((b * 8 + step) * 64 + n) * 4 + d] = a;
    Y[ln][d] = a;                 // keep nxt in LDS for conv phase
  }
  __syncthreads();
  if (step < 7) {
    int ln = tid >> 4, lane = tid & 15;
    int gid = b * 64 + n0 + ln;
    float* mycp = cp + ln * 160;
    mycp[lane] = win[gid * WROW + (step + 1) * 4 + lane];
    if (lane < 4) mycp[16 + lane] = Y[ln][lane];
    __syncthreads();
    conv_proj<16>(lane, gid, mycp, cw1, cb1, cw2, cb2, ew1, an, bn);
  }
}

extern "C" void kernel_launch(void* const* d_in, const int* in_sizes, int n_in,
                              void* d_out, int out_size, void* d_ws, size_t ws_size,
                              hipStream_t stream) {
  (void)in_sizes; (void)n_in; (void)out_size; (void)ws_size;
  const float* ts  = (const float*)d_in[0];
  const float* cw1 = (const float*)d_in[1];
  const float* cb1 = (const float*)d_in[2];
  const float* cw2 = (const float*)d_in[3];
  const float* cb2 = (const float*)d_in[4];
  const float* ew1 = (const float*)d_in[5];
  const float* eb1 = (const float*)d_in[6];
  const float* ew2 = (const float*)d_in[7];
  const float* eb2 = (const float*)d_in[8];
  const float* nw1 = (const float*)d_in[9];
  const float* nb1 = (const float*)d_in[10];
  const float* nw2 = (const float*)d_in[11];
  const float* nb2 = (const float*)d_in[12];
  const float* dw1 = (const float*)d_in[13];
  const float* db1 = (const float*)d_in[14];
  const float* dw2 = (const float*)d_in[15];
  const float* db2 = (const float*)d_in[16];
  const float* ow  = (const float*)d_in[17];
  const float* ob  = (const float*)d_in[18];
  float* out = (float*)d_out;
  float* ws  = (float*)d_ws;
  float* win = ws;                       // 425984 floats
  float* an  = win + 425984;             // 1048576
  float* bn  = an + 1048576;             // 1048576
  float* nmb = bn + 1048576;             // 1048576
  half_t* Bh = (half_t*)(nmb + 1048576); // 16384 halves
  half_t* Bl = Bh + 16384;               // 16384 halves

  hipLaunchKernelGGL(k_bsplit, dim3(64), dim3(256), 0, stream, ew2, Bh, Bl);
  hipLaunchKernelGGL(k_init, dim3(512), dim3(256), 0, stream,
                     ts, cw1, cb1, cw2, cb2, ew1, win, an, bn);
  for (int k = 0; k < 8; ++k) {
    hipLaunchKernelGGL(k_edge_v4, dim3(512), dim3(256), 0, stream,
                       an, bn, eb1, eb2, Bh, Bl, nmb);
    hipLaunchKernelGGL(k_nd, dim3(512), dim3(256), 0, stream,
                       k, nmb, nw1, nb1, nw2, nb2, dw1, db1, dw2, db2,
                       ow, ob, cw1, cb1, cw2, cb2, ew1, win, an, bn, out);
  }
}

// Round 7
// 565.638 us; speedup vs baseline: 2.2773x; 1.2760x over previous
//
#include <hip/hip_runtime.h>

#define WROW 52   // 13 time slices * 4 feats per node
#define TG 16     // targets per k_edge block

typedef _Float16 half_t;
typedef _Float16 half8 __attribute__((ext_vector_type(8)));
typedef float f32x4 __attribute__((ext_vector_type(4)));

#define SC 0.0009765625f   // 2^-10 activation pre-scale (exact power of 2)

// pack two f32 -> two f16 (RTZ) as a 32-bit word
__device__ __forceinline__ unsigned pkrtz(float a, float b) {
  auto v = __builtin_amdgcn_cvt_pkrtz(a, b);   // __fp16 x2
  return *(unsigned*)&v;
}

// ---------------- conv (2 layers) + edge-input projection -------------------
// LANES threads per node. cp: per-node scratch 160 floats.
// an/bn are stored PRE-SCALED by SC.
template<int LANES>
__device__ __forceinline__ void conv_proj(
    int lane, int gid, float* cp,
    const float* __restrict__ cw1, const float* __restrict__ cb1,
    const float* __restrict__ cw2, const float* __restrict__ cb2,
    const float* __restrict__ ew1,
    float* __restrict__ an, float* __restrict__ bn)
{
  #pragma unroll
  for (int o = 0; o < 96 / LANES; ++o) {
    int idx = lane + o * LANES;
    int tt = idx >> 5, f = idx & 31;
    float a = cb1[f];
    #pragma unroll
    for (int kt = 0; kt < 3; ++kt)
      #pragma unroll
      for (int d = 0; d < 4; ++d)
        a = fmaf(cp[(tt + kt) * 4 + d], cw1[(kt * 4 + d) * 32 + f], a);
    cp[32 + idx] = fmaxf(a, 0.f);
  }
  __syncthreads();
  #pragma unroll
  for (int o = 0; o < 32 / LANES; ++o) {
    int f = lane + o * LANES;
    float a = cb2[f];
    #pragma unroll
    for (int kt = 0; kt < 3; ++kt)
      for (int f1 = 0; f1 < 32; ++f1)
        a = fmaf(cp[32 + kt * 32 + f1], cw2[(kt * 32 + f1) * 32 + f], a);
    cp[128 + f] = fmaxf(a, 0.f);
  }
  __syncthreads();
  #pragma unroll
  for (int o = 0; o < 128 / LANES; ++o) {
    int j = lane + o * LANES;
    float a = 0.f, bb = 0.f;
    for (int f = 0; f < 32; ++f) {
      float h = cp[128 + f];
      a  = fmaf(h, ew1[f * 128 + j], a);
      bb = fmaf(h, ew1[(32 + f) * 128 + j], bb);
    }
    an[gid * 128 + j] = a * SC;
    bn[gid * 128 + j] = bb * SC;
  }
}

// ---------------- k_init: transpose + step-0 conv/proj ---------------------
__global__ __launch_bounds__(256) void k_init(
    const float* __restrict__ ts,
    const float* __restrict__ cw1, const float* __restrict__ cb1,
    const float* __restrict__ cw2, const float* __restrict__ cb2,
    const float* __restrict__ ew1,
    float* __restrict__ win, float* __restrict__ an, float* __restrict__ bn)
{
  __shared__ float cp[16 * 160];
  int blk = blockIdx.x;
  int b = blk >> 2, n0 = (blk & 3) << 4;
  int tid = threadIdx.x;
  int ln = tid >> 4, lane = tid & 15;
  int n = n0 + ln;
  int gid = b * 64 + n;
  float* mycp = cp + ln * 160;
  for (int idx = lane; idx < 20; idx += 16) {
    int tt = idx >> 2, d = idx & 3;
    float v = ts[((b * 5 + tt) * 64 + n) * 4 + d];
    mycp[idx] = v;
    win[gid * WROW + idx] = v;
  }
  __syncthreads();
  conv_proj<16>(lane, gid, mycp, cw1, cb1, cw2, cb2, ew1, an, bn);
}

// ---------------- k_wsplit: 5 weight mats -> f16 hi/lo B-fragment layout ---
// mat 0: ew2, 1: nw1, 2: nw2, 3: dw1[4:132], 4: dw2. dst = base (10x16384 halves)
__global__ __launch_bounds__(256) void k_wsplit(
    const float* __restrict__ ew2, const float* __restrict__ nw1,
    const float* __restrict__ nw2, const float* __restrict__ dw1,
    const float* __restrict__ dw2, half_t* __restrict__ dst)
{
  int mat = blockIdx.x >> 6;
  const float* src = (mat == 0) ? ew2 : (mat == 1) ? nw1 : (mat == 2) ? nw2
                   : (mat == 3) ? (dw1 + 512) : dw2;
  half_t* dh = dst + mat * 2 * 16384;
  half_t* dl = dh + 16384;
  int g = (blockIdx.x & 63) * 256 + threadIdx.x;   // k*128+col
  int k = g >> 7, col = g & 127;
  float x = src[g];
  _Float16 hi = (_Float16)x;
  float lo = x - (float)hi;
  int c = col >> 4, kb = k >> 5, kk = k & 31;
  int lane = ((kk >> 3) << 4) | (col & 15);
  int j = kk & 7;
  int idx = ((c * 4 + kb) * 64 + lane) * 8 + j;
  dh[idx] = hi;
  dl[idx] = (_Float16)lo;
}

// ---------------- k_edge_v4: per (b, 16-target group) ----------------------
// an slice in REGISTERS; B fragments in REGISTERS; double-buffered sAh/sAl.
// C = 1024 * (Ah@Bh + Ah@Bl + Al@Bh), A = relu(anS + btS)  (pre-scaled 2^-10)
__global__ __launch_bounds__(256, 2) void k_edge_v4(
    const float* __restrict__ an, const float* __restrict__ bn,
    const float* __restrict__ eb1, const float* __restrict__ eb2,
    const half_t* __restrict__ Bh, const half_t* __restrict__ Bl,
    float* __restrict__ nm)
{
  __shared__ __align__(16) half_t sAh[2][8192];
  __shared__ __align__(16) half_t sAl[2][8192];
  __shared__ float s_bt[TG * 128];
  int blk = blockIdx.x;
  int b = blk & 127, t0 = (blk >> 7) * TG;
  int tid = threadIdx.x;
  int w = tid >> 6, lane = tid & 63;

  #pragma unroll
  for (int i = 0; i < TG * 128 / 256; ++i) {
    int idx = tid + (i << 8);
    int tt = idx >> 7, j = idx & 127;
    s_bt[idx] = bn[((b << 6) + t0 + tt) * 128 + j] + eb1[j] * SC;
  }

  float au[4][8];
  {
    int kb8 = tid >> 4, sl = tid & 15;
    #pragma unroll
    for (int it = 0; it < 4; ++it) {
      const float* ap = an + (b << 13) + ((it * 16 + sl) << 7) + (kb8 << 3);
      float4 x0 = *(const float4*)ap;
      float4 x1 = *(const float4*)(ap + 4);
      au[it][0] = x0.x; au[it][1] = x0.y; au[it][2] = x0.z; au[it][3] = x0.w;
      au[it][4] = x1.x; au[it][5] = x1.y; au[it][6] = x1.z; au[it][7] = x1.w;
    }
  }

  half8 rbh[2][4], rbl[2][4];
  #pragma unroll
  for (int cc = 0; cc < 2; ++cc)
    #pragma unroll
    for (int kb = 0; kb < 4; ++kb) {
      int c = w * 2 + cc;
      rbh[cc][kb] = *(const half8*)(Bh + ((c * 4 + kb) * 64 + lane) * 8);
      rbl[cc][kb] = *(const half8*)(Bl + ((c * 4 + kb) * 64 + lane) * 8);
    }

  float bias0 = eb2[(w * 2 + 0) * 16 + (lane & 15)];
  float bias1 = eb2[(w * 2 + 1) * 16 + (lane & 15)];

  auto do_split = [&](int tt, half_t* dh, half_t* dl) {
    const float* bp = s_bt + (tt << 7) + ((tid >> 4) << 3);
    float4 b0 = *(const float4*)bp;
    float4 b1 = *(const float4*)(bp + 4);
    float bs[8] = {b0.x, b0.y, b0.z, b0.w, b1.x, b1.y, b1.z, b1.w};
    #pragma unroll
    for (int it = 0; it < 4; ++it) {
      int u = tid + (it << 8);
      float h32[8], l32[8];
      #pragma unroll
      for (int i = 0; i < 8; ++i) {
        float x = fmaxf(au[it][i] + bs[i], 0.f);
        float h = __uint_as_float(__float_as_uint(x) & 0xffffe000u);
        h32[i] = h;
        l32[i] = x - h;
      }
      unsigned hw[4], lw[4];
      #pragma unroll
      for (int p = 0; p < 4; ++p) {
        hw[p] = pkrtz(h32[2 * p], h32[2 * p + 1]);
        lw[p] = pkrtz(l32[2 * p], l32[2 * p + 1]);
      }
      *(uint4*)(dh + u * 8) = make_uint4(hw[0], hw[1], hw[2], hw[3]);
      *(uint4*)(dl + u * 8) = make_uint4(lw[0], lw[1], lw[2], lw[3]);
    }
  };

  __syncthreads();
  do_split(0, sAh[0], sAl[0]);
  __syncthreads();

  for (int tt = 0; tt < TG; ++tt) {
    int p = tt & 1;
    if (tt + 1 < TG) do_split(tt + 1, sAh[p ^ 1], sAl[p ^ 1]);

    const half_t* ph = sAh[p];
    const half_t* pl = sAl[p];
    f32x4 acc[4][2];
    #pragma unroll
    for (int rr = 0; rr < 4; ++rr)
      #pragma unroll
      for (int cc = 0; cc < 2; ++cc)
        acc[rr][cc] = (f32x4){0.f, 0.f, 0.f, 0.f};

    #pragma unroll
    for (int kb = 0; kb < 4; ++kb) {
      half8 ah[4], al[4];
      #pragma unroll
      for (int rr = 0; rr < 4; ++rr) {
        ah[rr] = *(const half8*)(ph + ((rr * 4 + kb) * 64 + lane) * 8);
        al[rr] = *(const half8*)(pl + ((rr * 4 + kb) * 64 + lane) * 8);
      }
      #pragma unroll
      for (int cc = 0; cc < 2; ++cc)
        #pragma unroll
        for (int rr = 0; rr < 4; ++rr) {
          acc[rr][cc] = __builtin_amdgcn_mfma_f32_16x16x32_f16(ah[rr], rbh[cc][kb], acc[rr][cc], 0, 0, 0);
          acc[rr][cc] = __builtin_amdgcn_mfma_f32_16x16x32_f16(ah[rr], rbl[cc][kb], acc[rr][cc], 0, 0, 0);
          acc[rr][cc] = __builtin_amdgcn_mfma_f32_16x16x32_f16(al[rr], rbh[cc][kb], acc[rr][cc], 0, 0, 0);
        }
    }

    int t = t0 + tt;
    float csum0 = 0.f, csum1 = 0.f;
    int rowoff = (lane >> 4) * 4;
    #pragma unroll
    for (int rr = 0; rr < 4; ++rr) {
      int sbase = rr * 16 + rowoff;
      #pragma unroll
      for (int q = 0; q < 4; ++q) {
        int s = sbase + q;
        float y0 = acc[rr][0][q] * 1024.f + bias0;
        float y1 = acc[rr][1][q] * 1024.f + bias1;
        if (s != t) {
          csum0 += fmaxf(y0, 0.f);
          csum1 += fmaxf(y1, 0.f);
        }
      }
    }
    csum0 += __shfl_xor(csum0, 16, 64);
    csum0 += __shfl_xor(csum0, 32, 64);
    csum1 += __shfl_xor(csum1, 16, 64);
    csum1 += __shfl_xor(csum1, 32, 64);
    if (lane < 32)
      nm[((b << 6) + t) * 128 + w * 32 + lane] = (lane < 16) ? csum0 : csum1;
    __syncthreads();
  }
}

// ---------------- k_nd_mfma: node MLP + decoder via MFMA + head + conv -----
// 16 nodes/block, 512 blocks. 4 layers of [16x128]@[128x128] on matrix pipe.
__global__ __launch_bounds__(256) void k_nd_mfma(
    int step,
    const float* __restrict__ nm,
    const half_t* __restrict__ wsp,   // split weights base (Bh); mats 1..4 used
    const float* __restrict__ nb1, const float* __restrict__ nb2,
    const float* __restrict__ dw1, const float* __restrict__ db1,
    const float* __restrict__ db2,
    const float* __restrict__ ow,  const float* __restrict__ ob,
    const float* __restrict__ cw1, const float* __restrict__ cb1,
    const float* __restrict__ cw2, const float* __restrict__ cb2,
    const float* __restrict__ ew1,
    float* __restrict__ win, float* __restrict__ an, float* __restrict__ bn,
    float* __restrict__ out)
{
  __shared__ __align__(16) float Xraw[16][132];
  __shared__ __align__(16) half_t sAh[2048];
  __shared__ __align__(16) half_t sAl[2048];
  __shared__ float sP[16][4];
  __shared__ float s_dw1a[4 * 128];
  __shared__ float s_nxt[16][4];
  __shared__ float cp[16 * 160];

  int blk = blockIdx.x;
  int b = blk >> 2, n0 = (blk & 3) << 4;
  int tid = threadIdx.x;
  int w = tid >> 6, lane = tid & 63;

  // stage X = nm rows (coalesced float4), P, dw1 first 4 rows
  #pragma unroll
  for (int i = 0; i < 2; ++i) {
    int idx = tid + (i << 8);              // 512 float4s
    int row = idx >> 5, jf = idx & 31;
    *(float4*)&Xraw[row][jf << 2] =
        *(const float4*)(nm + ((b * 64 + n0 + row) << 7) + (jf << 2));
  }
  if (tid < 64) {
    int ln = tid >> 2, d = tid & 3;
    sP[ln][d] = win[(b * 64 + n0 + ln) * WROW + (step + 4) * 4 + d];
  }
  for (int idx = tid; idx < 512; idx += 256) s_dw1a[idx] = dw1[idx];
  __syncthreads();

  // split Xraw (scaled by SC) -> A-fragments, write-linear
  auto splitX = [&]() {
    int kb = tid >> 6, l = tid & 63;
    int row = l & 15, k0 = (kb << 5) + ((l >> 4) << 3);
    float h32[8], l32[8];
    #pragma unroll
    for (int i = 0; i < 8; ++i) {
      float x = Xraw[row][k0 + i] * SC;
      float h = __uint_as_float(__float_as_uint(x) & 0xffffe000u);
      h32[i] = h;
      l32[i] = x - h;
    }
    unsigned hw[4], lw[4];
    #pragma unroll
    for (int p = 0; p < 4; ++p) {
      hw[p] = pkrtz(h32[2 * p], h32[2 * p + 1]);
      lw[p] = pkrtz(l32[2 * p], l32[2 * p + 1]);
    }
    *(uint4*)(sAh + tid * 8) = make_uint4(hw[0], hw[1], hw[2], hw[3]);
    *(uint4*)(sAl + tid * 8) = make_uint4(lw[0], lw[1], lw[2], lw[3]);
  };

  // one dense layer: Xraw <- relu(Xraw @ W + bias [+ P@dw1a]), via MFMA
  auto layerM = [&](const half_t* Wh, const half_t* Wl,
                    const float* bias, bool withP) {
    splitX();
    __syncthreads();
    #pragma unroll
    for (int cc = 0; cc < 2; ++cc) {
      int c = w * 2 + cc;
      int col = c * 16 + (lane & 15);
      int row0 = (lane >> 4) * 4;
      float bj = bias[col];
      f32x4 acc;
      #pragma unroll
      for (int q = 0; q < 4; ++q) {
        float v = bj;
        if (withP) {
          #pragma unroll
          for (int d = 0; d < 4; ++d)
            v = fmaf(sP[row0 + q][d], s_dw1a[d * 128 + col], v);
        }
        acc[q] = v * SC;
      }
      #pragma unroll
      for (int kb = 0; kb < 4; ++kb) {
        half8 ah = *(const half8*)(sAh + ((kb << 6) + lane) * 8);
        half8 al = *(const half8*)(sAl + ((kb << 6) + lane) * 8);
        half8 bh = *(const half8*)(Wh + ((c * 4 + kb) * 64 + lane) * 8);
        half8 bl = *(const half8*)(Wl + ((c * 4 + kb) * 64 + lane) * 8);
        acc = __builtin_amdgcn_mfma_f32_16x16x32_f16(ah, bh, acc, 0, 0, 0);
        acc = __builtin_amdgcn_mfma_f32_16x16x32_f16(ah, bl, acc, 0, 0, 0);
        acc = __builtin_amdgcn_mfma_f32_16x16x32_f16(al, bh, acc, 0, 0, 0);
      }
      #pragma unroll
      for (int q = 0; q < 4; ++q)
        Xraw[row0 + q][col] = fmaxf(acc[q] * 1024.f, 0.f);
    }
    __syncthreads();
  };

  const half_t* nh1 = wsp + 2 * 16384;  const half_t* nl1 = nh1 + 16384;
  const half_t* nh2 = wsp + 4 * 16384;  const half_t* nl2 = nh2 + 16384;
  const half_t* dh1 = wsp + 6 * 16384;  const half_t* dl1 = dh1 + 16384;
  const half_t* dh2 = wsp + 8 * 16384;  const half_t* dl2 = dh2 + 16384;

  layerM(nh1, nl1, nb1, false);   // node mlp 1
  layerM(nh2, nl2, nb2, false);   // node mlp 2
  layerM(dh1, dl1, db1, true);    // dec 1 (P part via dw1 rows 0..3)
  layerM(dh2, dl2, db2, false);   // dec 2

  // output head: nxt = X @ ow + ob + prev  (k split 4-ways + shfl reduce)
  {
    int ln = tid >> 4, d = (tid >> 2) & 3, kq = tid & 3;
    float cs = 0.f;
    #pragma unroll
    for (int i = 0; i < 32; ++i) {
      int k = (kq << 5) + i;
      cs = fmaf(Xraw[ln][k], ow[k * 4 + d], cs);
    }
    cs += __shfl_xor(cs, 1, 64);
    cs += __shfl_xor(cs, 2, 64);
    if ((tid & 3) == 0) {
      float a = cs + ob[d] + sP[ln][d];
      int n = n0 + ln, gid = b * 64 + n;
      win[gid * WROW + (step + 5) * 4 + d] = a;
      out[((b * 8 + step) * 64 + n) * 4 + d] = a;
      s_nxt[ln][d] = a;
    }
  }
  __syncthreads();

  if (step < 7) {
    int ln = tid >> 4, lane2 = tid & 15;
    int gid = b * 64 + n0 + ln;
    float* mycp = cp + ln * 160;
    mycp[lane2] = win[gid * WROW + (step + 1) * 4 + lane2];
    if (lane2 < 4) mycp[16 + lane2] = s_nxt[ln][lane2];
    __syncthreads();
    conv_proj<16>(lane2, gid, mycp, cw1, cb1, cw2, cb2, ew1, an, bn);
  }
}

extern "C" void kernel_launch(void* const* d_in, const int* in_sizes, int n_in,
                              void* d_out, int out_size, void* d_ws, size_t ws_size,
                              hipStream_t stream) {
  (void)in_sizes; (void)n_in; (void)out_size; (void)ws_size;
  const float* ts  = (const float*)d_in[0];
  const float* cw1 = (const float*)d_in[1];
  const float* cb1 = (const float*)d_in[2];
  const float* cw2 = (const float*)d_in[3];
  const float* cb2 = (const float*)d_in[4];
  const float* ew1 = (const float*)d_in[5];
  const float* eb1 = (const float*)d_in[6];
  const float* ew2 = (const float*)d_in[7];
  const float* eb2 = (const float*)d_in[8];
  const float* nw1 = (const float*)d_in[9];
  const float* nb1 = (const float*)d_in[10];
  const float* nw2 = (const float*)d_in[11];
  const float* nb2 = (const float*)d_in[12];
  const float* dw1 = (const float*)d_in[13];
  const float* db1 = (const float*)d_in[14];
  const float* dw2 = (const float*)d_in[15];
  const float* db2 = (const float*)d_in[16];
  const float* ow  = (const float*)d_in[17];
  const float* ob  = (const float*)d_in[18];
  float* out = (float*)d_out;
  float* ws  = (float*)d_ws;
  float* win = ws;                        // 425984 floats
  float* an  = win + 425984;              // 1048576
  float* bn  = an + 1048576;              // 1048576
  float* nmb = bn + 1048576;              // 1048576
  half_t* wsp = (half_t*)(nmb + 1048576); // 10 x 16384 halves (Bh,Bl,Nh1,...)
  half_t* Bh = wsp;
  half_t* Bl = Bh + 16384;

  hipLaunchKernelGGL(k_wsplit, dim3(320), dim3(256), 0, stream,
                     ew2, nw1, nw2, dw1, dw2, wsp);
  hipLaunchKernelGGL(k_init, dim3(512), dim3(256), 0, stream,
                     ts, cw1, cb1, cw2, cb2, ew1, win, an, bn);
  for (int k = 0; k < 8; ++k) {
    hipLaunchKernelGGL(k_edge_v4, dim3(512), dim3(256), 0, stream,
                       an, bn, eb1, eb2, Bh, Bl, nmb);
    hipLaunchKernelGGL(k_nd_mfma, dim3(512), dim3(256), 0, stream,
                       k, nmb, wsp, nb1, nb2, dw1, db1, db2,
                       ow, ob, cw1, cb1, cw2, cb2, ew1, win, an, bn, out);
  }
}